// Round 1
// baseline (73.062 us; speedup 1.0000x reference)
//
#include <hip/hip_runtime.h>

#define T_LEN 2048
#define S_LEN 512
#define D_LEN 128
#define BT 64
#define BG 64

// 256 threads: 16 (tx, g-dir) x 16 (ty, t-dir), 4x4 outputs per thread.
// LDS: two 64x128 fp32 tiles (64 KB total), XOR-swizzled on float4 columns
// to kill bank conflicts without padding.

__global__ __launch_bounds__(256, 2)
void mmd_kernel(const float* __restrict__ x, const float* __restrict__ init,
                float* __restrict__ out) {
    __shared__ float zt[BT * D_LEN];
    __shared__ float gt[BG * D_LEN];

    const int bt = blockIdx.y;      // t-tile: 0..31
    const int j  = blockIdx.x;      // g-tile within band: 0..8
    const int t0 = bt * BT;
    const int g0 = t0 + j * 64;     // g in [t0, t0+575] covers all s in [0,512)

    const int tid = threadIdx.x;

    // ---- stage z tile: rows t0..t0+63 (64 rows x 32 float4)
    for (int idx = tid; idx < BT * 32; idx += 256) {
        const int row = idx >> 5;
        const int c4  = idx & 31;
        const float4 v = *(const float4*)(x + (t0 + row) * D_LEN + c4 * 4);
        const int c4s = c4 ^ (row & 7);
        *(float4*)(zt + row * D_LEN + c4s * 4) = v;
    }
    // ---- stage G tile: rows g0..g0+63; G = [reverse(init) ; z[0:T-1]]
    for (int idx = tid; idx < BG * 32; idx += 256) {
        const int row = idx >> 5;
        const int c4  = idx & 31;
        const int g = g0 + row;
        const float* src = (g >= S_LEN) ? (x + (g - S_LEN) * D_LEN)
                                        : (init + (S_LEN - 1 - g) * D_LEN);
        const float4 v = *(const float4*)(src + c4 * 4);
        const int c4s = c4 ^ (row & 7);
        *(float4*)(gt + row * D_LEN + c4s * 4) = v;
    }
    __syncthreads();

    const int tx = tid & 15;   // g-dir
    const int ty = tid >> 4;   // t-dir

    float acc[4][4];
    #pragma unroll
    for (int i = 0; i < 4; ++i)
        #pragma unroll
        for (int jj = 0; jj < 4; ++jj) acc[i][jj] = 0.f;

    #pragma unroll 4
    for (int k4 = 0; k4 < 32; ++k4) {
        float4 za[4], wb[4];
        #pragma unroll
        for (int i = 0; i < 4; ++i) {
            const int row = i * 16 + ty;
            za[i] = *(const float4*)(zt + row * D_LEN + ((k4 ^ (row & 7)) << 2));
        }
        #pragma unroll
        for (int jj = 0; jj < 4; ++jj) {
            const int row = jj * 16 + tx;
            wb[jj] = *(const float4*)(gt + row * D_LEN + ((k4 ^ (row & 7)) << 2));
        }
        #pragma unroll
        for (int i = 0; i < 4; ++i) {
            #pragma unroll
            for (int jj = 0; jj < 4; ++jj) {
                const float dx = za[i].x - wb[jj].x;
                const float dy = za[i].y - wb[jj].y;
                const float dz = za[i].z - wb[jj].z;
                const float dw = za[i].w - wb[jj].w;
                acc[i][jj] += dx * dx + dy * dy + dz * dz + dw * dw;
            }
        }
    }

    // ---- epilogue: out[t][s], s = t + 511 - g, mask band edges
    #pragma unroll
    for (int i = 0; i < 4; ++i) {
        const int t = t0 + i * 16 + ty;
        #pragma unroll
        for (int jj = 0; jj < 4; ++jj) {
            const int g = g0 + jj * 16 + tx;
            const int s = t + (S_LEN - 1) - g;
            if (s >= 0 && s < S_LEN) {
                const float p = 1.f - acc[i][jj] * (1.f / (float)D_LEN);
                out[t * S_LEN + s] = p * p * p;
            }
        }
    }
}

extern "C" void kernel_launch(void* const* d_in, const int* in_sizes, int n_in,
                              void* d_out, int out_size, void* d_ws, size_t ws_size,
                              hipStream_t stream) {
    const float* x    = (const float*)d_in[0];   // (1,2048,1,128) -> (2048,128)
    const float* init = (const float*)d_in[1];   // (512,128)
    float* out = (float*)d_out;                  // (1,2048,512) fp32

    dim3 grid(9, 32);
    mmd_kernel<<<grid, 256, 0, stream>>>(x, init, out);
}

// Round 2
// 70.140 us; speedup vs baseline: 1.0417x; 1.0417x over previous
//
#include <hip/hip_runtime.h>

#define T_LEN 2048
#define S_LEN 512
#define D_LEN 128
#define BT 64
#define BG 64

// out[t][s] = (1 - ||z_t - G[t+511-s]||^2 / 128)^3
//   G[g] = init[511-g] (g<512), else x[g-512]
// Norm trick: ||z-w||^2 = ||z||^2 + ||w||^2 - 2 z.w  -> inner loop is pure FMA.
// 256 threads: 16x16, 4x4 outputs/thread, 64x64 (t x g) tiles.
// LDS XOR-swizzled on float4 columns: strided row reads are <=2-way (free).

__global__ __launch_bounds__(256, 2)
void mmd_kernel(const float* __restrict__ x, const float* __restrict__ init,
                float* __restrict__ out) {
    __shared__ float zt[BT * D_LEN];
    __shared__ float gt[BG * D_LEN];
    __shared__ float znorm[BT];
    __shared__ float gnorm[BG];

    const int bt = blockIdx.y;      // t-tile: 0..31
    const int j  = blockIdx.x;      // g-tile within band: 0..8
    const int t0 = bt * BT;
    const int g0 = t0 + j * 64;

    const int tid = threadIdx.x;

    // ---- stage z tile (64 rows x 32 float4), XOR swizzle
    for (int idx = tid; idx < BT * 32; idx += 256) {
        const int row = idx >> 5;
        const int c4  = idx & 31;
        const float4 v = *(const float4*)(x + (t0 + row) * D_LEN + c4 * 4);
        *(float4*)(zt + row * D_LEN + ((c4 ^ (row & 7)) << 2)) = v;
    }
    // ---- stage G tile
    for (int idx = tid; idx < BG * 32; idx += 256) {
        const int row = idx >> 5;
        const int c4  = idx & 31;
        const int g = g0 + row;
        const float* src = (g >= S_LEN) ? (x + (g - S_LEN) * D_LEN)
                                        : (init + (S_LEN - 1 - g) * D_LEN);
        const float4 v = *(const float4*)(src + c4 * 4);
        *(float4*)(gt + row * D_LEN + ((c4 ^ (row & 7)) << 2)) = v;
    }
    __syncthreads();

    // ---- row norms from LDS (threads 0..63: z rows, 64..127: g rows)
    if (tid < 128) {
        const int row = tid & 63;
        const float* base = (tid < 64) ? zt : gt;
        float s = 0.f;
        #pragma unroll 8
        for (int c4 = 0; c4 < 32; ++c4) {
            const float4 v = *(const float4*)(base + row * D_LEN + ((c4 ^ (row & 7)) << 2));
            s += v.x * v.x + v.y * v.y + v.z * v.z + v.w * v.w;
        }
        if (tid < 64) znorm[row] = s; else gnorm[row] = s;
    }
    __syncthreads();

    const int tx = tid & 15;   // g-dir
    const int ty = tid >> 4;   // t-dir

    float dot[4][4];
    #pragma unroll
    for (int i = 0; i < 4; ++i)
        #pragma unroll
        for (int jj = 0; jj < 4; ++jj) dot[i][jj] = 0.f;

    #pragma unroll 4
    for (int k4 = 0; k4 < 32; ++k4) {
        float4 za[4], wb[4];
        #pragma unroll
        for (int i = 0; i < 4; ++i) {
            const int row = i * 16 + ty;
            za[i] = *(const float4*)(zt + row * D_LEN + ((k4 ^ (row & 7)) << 2));
        }
        #pragma unroll
        for (int jj = 0; jj < 4; ++jj) {
            const int row = jj * 16 + tx;
            wb[jj] = *(const float4*)(gt + row * D_LEN + ((k4 ^ (row & 7)) << 2));
        }
        #pragma unroll
        for (int i = 0; i < 4; ++i) {
            #pragma unroll
            for (int jj = 0; jj < 4; ++jj) {
                dot[i][jj] += za[i].x * wb[jj].x + za[i].y * wb[jj].y
                            + za[i].z * wb[jj].z + za[i].w * wb[jj].w;
            }
        }
    }

    // ---- epilogue: dist = ||z||^2 + ||w||^2 - 2 dot; out[t][s], s = t+511-g
    #pragma unroll
    for (int i = 0; i < 4; ++i) {
        const int tr = i * 16 + ty;
        const int t  = t0 + tr;
        #pragma unroll
        for (int jj = 0; jj < 4; ++jj) {
            const int gr = jj * 16 + tx;
            const int g  = g0 + gr;
            const int s  = t + (S_LEN - 1) - g;
            if (s >= 0 && s < S_LEN) {
                const float dist = znorm[tr] + gnorm[gr] - 2.f * dot[i][jj];
                const float p = 1.f - dist * (1.f / (float)D_LEN);
                out[t * S_LEN + s] = p * p * p;
            }
        }
    }
}

extern "C" void kernel_launch(void* const* d_in, const int* in_sizes, int n_in,
                              void* d_out, int out_size, void* d_ws, size_t ws_size,
                              hipStream_t stream) {
    const float* x    = (const float*)d_in[0];   // (1,2048,1,128) -> (2048,128)
    const float* init = (const float*)d_in[1];   // (512,128)
    float* out = (float*)d_out;                  // (1,2048,512) fp32

    dim3 grid(9, 32);
    mmd_kernel<<<grid, 256, 0, stream>>>(x, init, out);
}